// Round 22
// baseline (333.887 us; speedup 1.0000x reference)
//
#include <hip/hip_runtime.h>
#include <math.h>

// PixelQueryNet v22 = v19 (245us) + depth-2-ahead LDS pipeline (3 static sets).
// R21 post-mortem: v21's "LDS halving" was an arithmetic error (inst count
// unchanged); consistent accounting says the ~300k cy non-VALU wall is per-ci
// ds_read latency (~300-400cy effective) that depth-1 lookahead can't cover.
// v22 issues reads for ci+2 before FMAs of ci: every read gets >=256cy cover.
// Sets S0/S1/S2 rotate with COMPILE-TIME indices (no runtime reg selects).
//
// Per low-res cell (b,i,j): MLP 4->64->64->64->64->3 (leaky 0.01, tanh) on the
// 64 pixels of its 8x8 tile; weights from lr_params[b,c,i,j] (stride 4096 fl).
// Block = 256 thr = 4 cells(j) x 8 px-rows(pg) x 8 co-blocks(cob); y[8co][8px]
// fp32 in registers. A = two unpadded fp32 k-planes (lane-contiguous b128).
// WB = 16KB ring, 2 halves x 4 tiles, XOR-swizzled rows (conflicts ~0).
// LDS 80KB -> 2 blocks/CU. Grid 2048; siblings n,n+8,n+16,n+24 (same XCD)
// share each 64B weight line -> FETCH ideal. One barrier per group.

static constexpr int PLANE = 4096;
static constexpr int NPAR  = 12995;
static constexpr int AHI   = 8192;  // word offset of k4..7 plane

__device__ __forceinline__ float leaky(float v) { return fmaxf(v, 0.01f * v); }

// PE x-features, compile-time: cos/sin(2*pi*k/8), k = dx.
__device__ __forceinline__ constexpr float cx(int k) {
  constexpr float R = 0.70710678118654752f;
  const float t[8] = {1.f, R, 0.f, -R, -1.f, -R, 0.f, R};
  return t[k];
}
__device__ __forceinline__ constexpr float sx(int k) {
  constexpr float R = 0.70710678118654752f;
  const float t[8] = {0.f, R, 1.f, R, 0.f, -R, -1.f, -R};
  return t[k];
}

__global__ __launch_bounds__(256, 1) void pqn(const float* __restrict__ lr,
                                              float* __restrict__ out) {
  __shared__ alignas(16) float A[2 * AHI];     // 65536 B activations (fp32)
  __shared__ alignas(16) float WB[2][2048];    // 16384 B ring: 2 halves x 4 tiles

  const int tid = threadIdx.x;
  const int j   = tid & 3;
  const int pg  = (tid >> 2) & 7;      // pixel row (dy)
  const int cob = tid >> 5;            // 0..7

  // ---- swizzle: 4 siblings (same XCD) cover one 64B weight line
  const int n  = blockIdx.x;
  const int e2 = (n >> 3) & 3;
  const int P  = (n & 7) | ((n >> 5) << 3);   // 0..511
  const int jg = ((P & 3) << 2) | e2;         // 0..15
  const int i  = (P >> 2) & 63;
  const int b  = (P >> 8) & 1;

  const float* __restrict__ wb =
      lr + (size_t)b * NPAR * PLANE + (size_t)(i * 64 + jg * 4);
  const float* __restrict__ pt = wb + j;      // per-thread channel base

  float fyc, fys;
  sincosf(0.78539816339744830962f * pg, &fys, &fyc);

  const int abase = pg * 16 + j * 4;   // lane-contiguous A offset
  const int swz   = j * 4;             // weight-row XOR swizzle
  const int sq    = tid >> 7;          // staging: which tile-pair half
  const int sc    = tid & 127;         // staging channel within tile

  auto gaddr = [&](int g) -> size_t {  // first channel of group g's weights
    return 384 + (size_t)(g >> 3) * 4160 + (size_t)(g & 7) * 512;
  };

  float4 paA, paB;                     // single staging pair (1-group flight)
  {
    const size_t cb = gaddr(0);
    paA = *(const float4*)(wb + (cb + tid) * PLANE);
    paB = *(const float4*)(wb + (cb + 256 + tid) * PLANE);
  }
  float l0b[8], l0w[32], bb[8];
#pragma unroll
  for (int m = 0; m < 8; ++m) l0b[m] = pt[(size_t)(cob * 8 + m) * PLANE];
#pragma unroll
  for (int f = 0; f < 4; ++f)
#pragma unroll
    for (int m = 0; m < 8; ++m)
      l0w[f * 8 + m] = pt[(size_t)(64 + f * 64 + cob * 8 + m) * PLANE];
#pragma unroll
  for (int m = 0; m < 8; ++m) bb[m] = pt[(size_t)(320 + cob * 8 + m) * PLANE];

  // ---- L0 compute -> A
#pragma unroll
  for (int col = 0; col < 8; ++col) {
    float t[8];
#pragma unroll
    for (int k = 0; k < 8; ++k) {
      float v = l0b[col];
      v = fmaf(cx(k), l0w[col], v);
      v = fmaf(sx(k), l0w[8 + col], v);
      v = fmaf(fyc,  l0w[16 + col], v);
      v = fmaf(fys,  l0w[24 + col], v);
      t[k] = leaky(v);
    }
    float4 v0, v1;
    v0.x = t[0]; v0.y = t[1]; v0.z = t[2]; v0.w = t[3];
    v1.x = t[4]; v1.y = t[5]; v1.z = t[6]; v1.w = t[7];
    *(float4*)&A[(cob * 8 + col) * 128 + abase]       = v0;
    *(float4*)&A[(cob * 8 + col) * 128 + abase + AHI] = v1;
  }
  // publish group 0 -> half 0; refill Pa <- g1
#pragma unroll
  for (int jj = 0; jj < 4; ++jj) {
    WB[0][sq * 512       + jj * 128 + (sc ^ (jj * 4))] = ((const float*)&paA)[jj];
    WB[0][(2 + sq) * 512 + jj * 128 + (sc ^ (jj * 4))] = ((const float*)&paB)[jj];
  }
  {
    const size_t cb = gaddr(1);
    paA = *(const float4*)(wb + (cb + tid) * PLANE);
    paB = *(const float4*)(wb + (cb + 256 + tid) * PLANE);
  }
  asm volatile("s_waitcnt lgkmcnt(0)" ::: "memory");
  __builtin_amdgcn_s_barrier();
  __builtin_amdgcn_sched_barrier(0);

  float y[64];
#pragma unroll
  for (int m = 0; m < 64; ++m) y[m] = 0.f;

// read set S with data of ci-step T (compile-time T)
#define RD(S, T)                                                               \
  {                                                                            \
    const int ci_ = r0 + (T);                                                  \
    const int q_ = (T) >> 1, cl_ = (T) & 1;                                    \
    S##a0 = *(const float4*)&A[ci_ * 128 + abase];                             \
    S##a1 = *(const float4*)&A[ci_ * 128 + abase + AHI];                       \
    S##w0 = *(const float4*)&WH[q_ * 512 + j * 128 +                           \
                                ((cl_ * 64 + cob * 8) ^ swz)];                 \
    S##w1 = *(const float4*)&WH[q_ * 512 + j * 128 +                           \
                                ((cl_ * 64 + cob * 8 + 4) ^ swz)];             \
  }
// 64 FMAs consuming set S
#define FM(S)                                                                  \
  {                                                                            \
    const float av_[8] = {S##a0.x, S##a0.y, S##a0.z, S##a0.w,                  \
                          S##a1.x, S##a1.y, S##a1.z, S##a1.w};                 \
    const float wv_[8] = {S##w0.x, S##w0.y, S##w0.z, S##w0.w,                  \
                          S##w1.x, S##w1.y, S##w1.z, S##w1.w};                 \
    _Pragma("unroll")                                                          \
    for (int col = 0; col < 8; ++col)                                          \
      _Pragma("unroll")                                                        \
      for (int k = 0; k < 8; ++k)                                              \
        y[col * 8 + k] = fmaf(av_[k], wv_[col], y[col * 8 + k]);               \
  }

  // one full group: depth-2-ahead pipeline over the 8 ci-steps
  auto group = [&](int g, int h) {     // h = g&1 (literal at call sites)
    const float* WH = WB[h];
    const int r0 = (g & 7) * 8;
    float4 s0a0, s0a1, s0w0, s0w1;
    float4 s1a0, s1a1, s1w0, s1w1;
    float4 s2a0, s2a1, s2w0, s2w1;
    RD(s0, 0) RD(s1, 1)                // primes at LDS-queue head
    if (g + 1 < 24) {                  // publish g+1 from Pa -> other half
      float* WD = WB[h ^ 1];
#pragma unroll
      for (int jj = 0; jj < 4; ++jj) {
        WD[sq * 512       + jj * 128 + (sc ^ (jj * 4))] = ((const float*)&paA)[jj];
        WD[(2 + sq) * 512 + jj * 128 + (sc ^ (jj * 4))] = ((const float*)&paB)[jj];
      }
    }
    if (g + 2 < 24) {                  // refill Pa <- g+2 (1.5-slot flight)
      const size_t cb = gaddr(g + 2);
      paA = *(const float4*)(wb + (cb + tid) * PLANE);
      paB = *(const float4*)(wb + (cb + 256 + tid) * PLANE);
    }
    RD(s2, 2) FM(s0)
    RD(s0, 3) FM(s1)
    RD(s1, 4) FM(s2)
    RD(s2, 5) FM(s0)
    RD(s0, 6) FM(s1)
    RD(s1, 7) FM(s2)
    FM(s0)
    FM(s1)
    asm volatile("s_waitcnt lgkmcnt(0)" ::: "memory");
    __builtin_amdgcn_s_barrier();
    __builtin_amdgcn_sched_barrier(0);
  };
  auto flush = [&](int l) {            // layer end: bias + leaky -> A
#pragma unroll
    for (int col = 0; col < 8; ++col) {
      float4 v0, v1;
      v0.x = leaky(y[col * 8 + 0] + bb[col]);
      v0.y = leaky(y[col * 8 + 1] + bb[col]);
      v0.z = leaky(y[col * 8 + 2] + bb[col]);
      v0.w = leaky(y[col * 8 + 3] + bb[col]);
      v1.x = leaky(y[col * 8 + 4] + bb[col]);
      v1.y = leaky(y[col * 8 + 5] + bb[col]);
      v1.z = leaky(y[col * 8 + 6] + bb[col]);
      v1.w = leaky(y[col * 8 + 7] + bb[col]);
      *(float4*)&A[(cob * 8 + col) * 128 + abase]       = v0;
      *(float4*)&A[(cob * 8 + col) * 128 + abase + AHI] = v1;
    }
#pragma unroll
    for (int m = 0; m < 64; ++m) y[m] = 0.f;
    if (l < 2) {
#pragma unroll
      for (int m = 0; m < 8; ++m)
        bb[m] = pt[(size_t)(320 + (l + 1) * 4160 + cob * 8 + m) * PLANE];
    }
  };

  // ---- 12 super-iterations of 2 groups; ring half STATIC per position
#pragma unroll 1
  for (int u = 0; u < 12; ++u) {
    const int g0 = u * 2;
    group(g0, 0);
    const int g1 = g0 + 1;
    group(g1, 1);
    if ((g1 & 7) == 7) {               // layer end: flush + extra barrier
      flush(g1 >> 3);
      asm volatile("s_waitcnt lgkmcnt(0)" ::: "memory");
      __builtin_amdgcn_s_barrier();
      __builtin_amdgcn_sched_barrier(0);
    }
  }
#undef RD
#undef FM

  // ---- epilogue: L4 (64 -> 3) + tanh
  float po[24];
#pragma unroll
  for (int m = 0; m < 24; ++m) po[m] = 0.f;
#pragma unroll
  for (int cl = 0; cl < 8; ++cl) {
    const int ci = cob * 8 + cl;
    const float4 a0 = *(const float4*)&A[ci * 128 + abase];
    const float4 a1 = *(const float4*)&A[ci * 128 + abase + AHI];
#pragma unroll
    for (int o = 0; o < 3; ++o) {
      const float w = pt[(size_t)(12803 + ci * 3 + o) * PLANE];
      po[o * 8 + 0] = fmaf(a0.x, w, po[o * 8 + 0]);
      po[o * 8 + 1] = fmaf(a0.y, w, po[o * 8 + 1]);
      po[o * 8 + 2] = fmaf(a0.z, w, po[o * 8 + 2]);
      po[o * 8 + 3] = fmaf(a0.w, w, po[o * 8 + 3]);
      po[o * 8 + 4] = fmaf(a1.x, w, po[o * 8 + 4]);
      po[o * 8 + 5] = fmaf(a1.y, w, po[o * 8 + 5]);
      po[o * 8 + 6] = fmaf(a1.z, w, po[o * 8 + 6]);
      po[o * 8 + 7] = fmaf(a1.w, w, po[o * 8 + 7]);
    }
  }
  asm volatile("s_waitcnt lgkmcnt(0)" ::: "memory");
  __builtin_amdgcn_s_barrier();        // all A reads done -> reuse A
  float* R = A;
#pragma unroll
  for (int m = 0; m < 24; m += 4)
    *(float4*)&R[tid * 28 + m] = *(float4*)&po[m];
  asm volatile("s_waitcnt lgkmcnt(0)" ::: "memory");
  __builtin_amdgcn_s_barrier();
  __builtin_amdgcn_sched_barrier(0);

  if (cob == 0) {                      // tid < 32: one (j, pg) per thread
#pragma unroll
    for (int o = 0; o < 3; ++o) {
      const float bias = pt[(size_t)(12800 + o) * PLANE];
      float s[8];
#pragma unroll
      for (int k = 0; k < 8; ++k) s[k] = bias;
#pragma unroll
      for (int cb = 0; cb < 8; ++cb) {
#pragma unroll
        for (int k = 0; k < 8; ++k)
          s[k] += R[(cb * 32 + tid) * 28 + o * 8 + k];
      }
      float4 v0, v1;
      v0.x = tanhf(s[0]); v0.y = tanhf(s[1]); v0.z = tanhf(s[2]); v0.w = tanhf(s[3]);
      v1.x = tanhf(s[4]); v1.y = tanhf(s[5]); v1.z = tanhf(s[6]); v1.w = tanhf(s[7]);
      float* op = out + (size_t)b * 786432 + (size_t)o * 262144 +
                  (size_t)(i * 8 + pg) * 512 + (size_t)((jg * 4 + j) * 8);
      *(float4*)op = v0;
      *(float4*)(op + 4) = v1;
    }
  }
}

extern "C" void kernel_launch(void* const* d_in, const int* in_sizes, int n_in,
                              void* d_out, int out_size, void* d_ws, size_t ws_size,
                              hipStream_t stream) {
  (void)in_sizes; (void)n_in; (void)d_ws; (void)ws_size; (void)out_size;
  const float* lr = (const float*)d_in[1];  // d_in[0] = highres (unused by the math)
  float* out = (float*)d_out;
  hipLaunchKernelGGL(pqn, dim3(2048), dim3(256), 0, stream, lr, out);
}

// Round 23
// 332.154 us; speedup vs baseline: 1.0052x; 1.0052x over previous
//
#include <hip/hip_runtime.h>
#include <math.h>

// PixelQueryNet v23 = v19 math/pipeline, halved blocks -> 4 barrier domains/CU.
// R22 corrected accounting: VALU ~50%, LDS ~50%, neither saturated; the wall
// is per-wave read->FMA serialization with only 2 independent barrier domains
// per CU. v23: 2-cell/128-thr blocks (2 waves), LDS 40960 B exactly ->
// 4 blocks/CU = 4 independent domains; same per-thread tile (8co x 8k).
//
// Per low-res cell (b,i,j): MLP 4->64->64->64->64->3 (leaky 0.01, tanh) on the
// 64 pixels of its 8x8 tile; weights from lr_params[b,c,i,j] (stride 4096 fl).
// Thread map: j = tid&1 (cell in pair), pg = (tid>>1)&7, cob = tid>>4 (0..7).
// A: word = ci*64 + pg*8 + j*4 (+AHI=4096 for k4..7): 16 distinct quads,
//   4-way broadcast, 2-way banks (free). 32 KB.
// WB ring: [2][1024] words; tile q (2 ci): word q*256 + j*128 + cl*64 + co.
//   reads 8 quads/wave, 2-way banks (free); publish 8 b32/thread, 2-way.
// Staging: 4 float2/thread (channels tid+128t, j-pair 8B contiguous);
//   siblings n,n+8..n+56 (same XCD) cover each 64B line -> FETCH ideal.
// One barrier/group (ring halves disjoint), 24 groups, flush at 3 layer ends.

static constexpr int PLANE = 4096;
static constexpr int NPAR  = 12995;
static constexpr int AHI   = 4096;  // word offset of k4..7 plane

__device__ __forceinline__ float leaky(float v) { return fmaxf(v, 0.01f * v); }

// PE x-features, compile-time: cos/sin(2*pi*k/8), k = dx.
__device__ __forceinline__ constexpr float cx(int k) {
  constexpr float R = 0.70710678118654752f;
  const float t[8] = {1.f, R, 0.f, -R, -1.f, -R, 0.f, R};
  return t[k];
}
__device__ __forceinline__ constexpr float sx(int k) {
  constexpr float R = 0.70710678118654752f;
  const float t[8] = {0.f, R, 1.f, R, 0.f, -R, -1.f, -R};
  return t[k];
}

__global__ __launch_bounds__(128, 1) void pqn(const float* __restrict__ lr,
                                              float* __restrict__ out) {
  __shared__ alignas(16) float A[2 * AHI];     // 32768 B activations (fp32)
  __shared__ alignas(16) float WB[2][1024];    // 8192 B ring: 2 halves x 4 tiles

  const int tid = threadIdx.x;
  const int j   = tid & 1;
  const int pg  = (tid >> 1) & 7;      // pixel row (dy)
  const int cob = tid >> 4;            // 0..7

  // ---- swizzle: 8 siblings (same XCD) cover one 64B weight line
  const int n  = blockIdx.x;
  const int e3 = (n >> 3) & 7;
  const int P  = (n & 7) | ((n >> 6) << 3);   // 0..511
  const int jp = ((P & 3) << 3) | e3;         // 0..31 (j-pair)
  const int i  = (P >> 2) & 63;
  const int b  = (P >> 8) & 1;

  const float* __restrict__ wb =
      lr + (size_t)b * NPAR * PLANE + (size_t)(i * 64 + jp * 2);
  const float* __restrict__ pt = wb + j;      // per-thread channel base

  float fyc, fys;
  sincosf(0.78539816339744830962f * pg, &fys, &fyc);

  const int abase = pg * 8 + j * 4;    // A offset within a ci slice
  const int wrd   = j * 128 + cob * 8; // W read base (+ q*256 + cl*64)

  auto gaddr = [&](int g) -> size_t {  // first channel of group g's weights
    return 384 + (size_t)(g >> 3) * 4160 + (size_t)(g & 7) * 512;
  };

  float2 pa0, pa1, pa2, pa3;           // staging: 4 channels x j-pair
  {
    const size_t cb = gaddr(0);
    pa0 = *(const float2*)(wb + (cb + tid) * PLANE);
    pa1 = *(const float2*)(wb + (cb + 128 + tid) * PLANE);
    pa2 = *(const float2*)(wb + (cb + 256 + tid) * PLANE);
    pa3 = *(const float2*)(wb + (cb + 384 + tid) * PLANE);
  }
  float l0b[8], l0w[32], bb[8];
#pragma unroll
  for (int m = 0; m < 8; ++m) l0b[m] = pt[(size_t)(cob * 8 + m) * PLANE];
#pragma unroll
  for (int f = 0; f < 4; ++f)
#pragma unroll
    for (int m = 0; m < 8; ++m)
      l0w[f * 8 + m] = pt[(size_t)(64 + f * 64 + cob * 8 + m) * PLANE];
#pragma unroll
  for (int m = 0; m < 8; ++m) bb[m] = pt[(size_t)(320 + cob * 8 + m) * PLANE];

  // ---- L0 compute -> A
#pragma unroll
  for (int col = 0; col < 8; ++col) {
    float t[8];
#pragma unroll
    for (int k = 0; k < 8; ++k) {
      float v = l0b[col];
      v = fmaf(cx(k), l0w[col], v);
      v = fmaf(sx(k), l0w[8 + col], v);
      v = fmaf(fyc,  l0w[16 + col], v);
      v = fmaf(fys,  l0w[24 + col], v);
      t[k] = leaky(v);
    }
    float4 v0, v1;
    v0.x = t[0]; v0.y = t[1]; v0.z = t[2]; v0.w = t[3];
    v1.x = t[4]; v1.y = t[5]; v1.z = t[6]; v1.w = t[7];
    *(float4*)&A[(cob * 8 + col) * 64 + abase]       = v0;
    *(float4*)&A[(cob * 8 + col) * 64 + abase + AHI] = v1;
  }
  // publish group 0 -> half 0; refill <- g1.  channel c = tid + 128t -> tile t
#define PUBLISH(WD)                                                            \
  {                                                                            \
    (WD)[tid]             = pa0.x; (WD)[128 + tid]       = pa0.y;              \
    (WD)[256 + tid]       = pa1.x; (WD)[256 + 128 + tid] = pa1.y;              \
    (WD)[512 + tid]       = pa2.x; (WD)[512 + 128 + tid] = pa2.y;              \
    (WD)[768 + tid]       = pa3.x; (WD)[768 + 128 + tid] = pa3.y;              \
  }
#define REFILL(G)                                                              \
  {                                                                            \
    const size_t cb_ = gaddr(G);                                               \
    pa0 = *(const float2*)(wb + (cb_ + tid) * PLANE);                          \
    pa1 = *(const float2*)(wb + (cb_ + 128 + tid) * PLANE);                    \
    pa2 = *(const float2*)(wb + (cb_ + 256 + tid) * PLANE);                    \
    pa3 = *(const float2*)(wb + (cb_ + 384 + tid) * PLANE);                    \
  }
  PUBLISH(WB[0])
  REFILL(1)
  asm volatile("s_waitcnt lgkmcnt(0)" ::: "memory");
  __builtin_amdgcn_s_barrier();
  __builtin_amdgcn_sched_barrier(0);

  float y[64];
#pragma unroll
  for (int m = 0; m < 64; ++m) y[m] = 0.f;

  // one full group: publish g+1 -> other half, refill <- g+2, then the
  // depth-1 per-ci pipeline (v19's 245us structure)
  auto group = [&](int g, int h) {     // h = g&1 (literal at call sites)
    if (g + 1 < 24) PUBLISH(WB[h ^ 1])
    if (g + 2 < 24) REFILL(g + 2)
    const float* WH = WB[h];
    // prime ci-step 0 (q=0, cl=0)
    float4 a0 = *(const float4*)&A[((g & 7) * 8) * 64 + abase];
    float4 a1 = *(const float4*)&A[((g & 7) * 8) * 64 + abase + AHI];
    float4 w0 = *(const float4*)&WH[wrd];
    float4 w1 = *(const float4*)&WH[wrd + 4];
    const int r0 = (g & 7) * 8;
#pragma unroll
    for (int t = 0; t < 8; ++t) {
      float4 na0, na1, nw0, nw1;
      if (t < 7) {                     // issue ci+1's reads BEFORE FMAs
        const int tn = t + 1;
        const int ci = r0 + tn;
        const int q = tn >> 1, cl = tn & 1;
        na0 = *(const float4*)&A[ci * 64 + abase];
        na1 = *(const float4*)&A[ci * 64 + abase + AHI];
        nw0 = *(const float4*)&WH[q * 256 + wrd + cl * 64];
        nw1 = *(const float4*)&WH[q * 256 + wrd + cl * 64 + 4];
      }
      const float av[8] = {a0.x, a0.y, a0.z, a0.w, a1.x, a1.y, a1.z, a1.w};
      const float wv[8] = {w0.x, w0.y, w0.z, w0.w, w1.x, w1.y, w1.z, w1.w};
#pragma unroll
      for (int col = 0; col < 8; ++col)
#pragma unroll
        for (int k = 0; k < 8; ++k)
          y[col * 8 + k] = fmaf(av[k], wv[col], y[col * 8 + k]);
      if (t < 7) { a0 = na0; a1 = na1; w0 = nw0; w1 = nw1; }
    }
    asm volatile("s_waitcnt lgkmcnt(0)" ::: "memory");
    __builtin_amdgcn_s_barrier();
    __builtin_amdgcn_sched_barrier(0);
  };
  auto flush = [&](int l) {            // layer end: bias + leaky -> A
#pragma unroll
    for (int col = 0; col < 8; ++col) {
      float4 v0, v1;
      v0.x = leaky(y[col * 8 + 0] + bb[col]);
      v0.y = leaky(y[col * 8 + 1] + bb[col]);
      v0.z = leaky(y[col * 8 + 2] + bb[col]);
      v0.w = leaky(y[col * 8 + 3] + bb[col]);
      v1.x = leaky(y[col * 8 + 4] + bb[col]);
      v1.y = leaky(y[col * 8 + 5] + bb[col]);
      v1.z = leaky(y[col * 8 + 6] + bb[col]);
      v1.w = leaky(y[col * 8 + 7] + bb[col]);
      *(float4*)&A[(cob * 8 + col) * 64 + abase]       = v0;
      *(float4*)&A[(cob * 8 + col) * 64 + abase + AHI] = v1;
    }
#pragma unroll
    for (int m = 0; m < 64; ++m) y[m] = 0.f;
    if (l < 2) {
#pragma unroll
      for (int m = 0; m < 8; ++m)
        bb[m] = pt[(size_t)(320 + (l + 1) * 4160 + cob * 8 + m) * PLANE];
    }
  };

  // ---- 12 super-iterations of 2 groups; ring half STATIC per position
#pragma unroll 1
  for (int u = 0; u < 12; ++u) {
    const int g0 = u * 2;
    group(g0, 0);
    const int g1 = g0 + 1;
    group(g1, 1);
    if ((g1 & 7) == 7) {               // layer end: flush + extra barrier
      flush(g1 >> 3);
      asm volatile("s_waitcnt lgkmcnt(0)" ::: "memory");
      __builtin_amdgcn_s_barrier();
      __builtin_amdgcn_sched_barrier(0);
    }
  }
#undef PUBLISH
#undef REFILL

  // ---- epilogue: L4 (64 -> 3) + tanh
  float po[24];
#pragma unroll
  for (int m = 0; m < 24; ++m) po[m] = 0.f;
#pragma unroll
  for (int cl = 0; cl < 8; ++cl) {
    const int ci = cob * 8 + cl;
    const float4 a0 = *(const float4*)&A[ci * 64 + abase];
    const float4 a1 = *(const float4*)&A[ci * 64 + abase + AHI];
#pragma unroll
    for (int o = 0; o < 3; ++o) {
      const float w = pt[(size_t)(12803 + ci * 3 + o) * PLANE];
      po[o * 8 + 0] = fmaf(a0.x, w, po[o * 8 + 0]);
      po[o * 8 + 1] = fmaf(a0.y, w, po[o * 8 + 1]);
      po[o * 8 + 2] = fmaf(a0.z, w, po[o * 8 + 2]);
      po[o * 8 + 3] = fmaf(a0.w, w, po[o * 8 + 3]);
      po[o * 8 + 4] = fmaf(a1.x, w, po[o * 8 + 4]);
      po[o * 8 + 5] = fmaf(a1.y, w, po[o * 8 + 5]);
      po[o * 8 + 6] = fmaf(a1.z, w, po[o * 8 + 6]);
      po[o * 8 + 7] = fmaf(a1.w, w, po[o * 8 + 7]);
    }
  }
  asm volatile("s_waitcnt lgkmcnt(0)" ::: "memory");
  __builtin_amdgcn_s_barrier();        // all A reads done -> reuse A
  float* R = A;                        // 128 thr x 28 = 3584 words <= 8192
#pragma unroll
  for (int m = 0; m < 24; m += 4)
    *(float4*)&R[tid * 28 + m] = *(float4*)&po[m];
  asm volatile("s_waitcnt lgkmcnt(0)" ::: "memory");
  __builtin_amdgcn_s_barrier();
  __builtin_amdgcn_sched_barrier(0);

  if (cob == 0) {                      // tid < 16: one (j, pg) per thread
#pragma unroll
    for (int o = 0; o < 3; ++o) {
      const float bias = pt[(size_t)(12800 + o) * PLANE];
      float s[8];
#pragma unroll
      for (int k = 0; k < 8; ++k) s[k] = bias;
#pragma unroll
      for (int cb = 0; cb < 8; ++cb) {
#pragma unroll
        for (int k = 0; k < 8; ++k)
          s[k] += R[(tid + cb * 16) * 28 + o * 8 + k];
      }
      float4 v0, v1;
      v0.x = tanhf(s[0]); v0.y = tanhf(s[1]); v0.z = tanhf(s[2]); v0.w = tanhf(s[3]);
      v1.x = tanhf(s[4]); v1.y = tanhf(s[5]); v1.z = tanhf(s[6]); v1.w = tanhf(s[7]);
      float* op = out + (size_t)b * 786432 + (size_t)o * 262144 +
                  (size_t)(i * 8 + pg) * 512 + (size_t)((jp * 2 + j) * 8);
      *(float4*)op = v0;
      *(float4*)(op + 4) = v1;
    }
  }
}

extern "C" void kernel_launch(void* const* d_in, const int* in_sizes, int n_in,
                              void* d_out, int out_size, void* d_ws, size_t ws_size,
                              hipStream_t stream) {
  (void)in_sizes; (void)n_in; (void)d_ws; (void)ws_size; (void)out_size;
  const float* lr = (const float*)d_in[1];  // d_in[0] = highres (unused by the math)
  float* out = (float*)d_out;
  hipLaunchKernelGGL(pqn, dim3(4096), dim3(128), 0, stream, lr, out);
}

// Round 24
// 239.331 us; speedup vs baseline: 1.3951x; 1.3878x over previous
//
#include <hip/hip_runtime.h>
#include <math.h>

// PixelQueryNet v24 = v19 (245.6us, best) + v_pk_fma_f32 packed inner loop.
// Per-CU accounting (consistent v14-v23): LDS pipe 295k cy + VALU 297k cy,
// ADDITIVE (6 rounds of overlap attempts null) = the 590k cy wall. pk_fma
// halves FMA issue (32 VOP3P/ci-step vs 64 VOP3): VALU -> ~210k cy.
// op_sel broadcasts the w half (even col: both lanes w.lo; odd: w.hi) so no
// extra movs; y2[32] float2 accumulators = same 64 VGPRs.
//
// Per low-res cell (b,i,j): MLP 4->64->64->64->64->3 (leaky 0.01, tanh) on the
// 64 pixels of its 8x8 tile; weights from lr_params[b,c,i,j] (stride 4096 fl).
// Block = 256 thr = 4 cells(j) x 8 px(pg) x 8 co-blocks(cob). A = two fp32
// k-planes (lane-contiguous b128, conflict-free). WB = 16KB ring, XOR-swizzled
// rows (conflicts 0). LDS 80KB -> 2 blocks/CU. Grid 2048; 4 XCD-siblings
// share each 64B weight line -> FETCH ideal. One barrier per group; depth-1
// per-ci LDS pipeline.

static constexpr int PLANE = 4096;
static constexpr int NPAR  = 12995;
static constexpr int AHI   = 8192;  // word offset of k4..7 plane

__device__ __forceinline__ float leaky(float v) { return fmaxf(v, 0.01f * v); }

// PE x-features, compile-time: cos/sin(2*pi*k/8), k = dx.
__device__ __forceinline__ constexpr float cx(int k) {
  constexpr float R = 0.70710678118654752f;
  const float t[8] = {1.f, R, 0.f, -R, -1.f, -R, 0.f, R};
  return t[k];
}
__device__ __forceinline__ constexpr float sx(int k) {
  constexpr float R = 0.70710678118654752f;
  const float t[8] = {0.f, R, 1.f, R, 0.f, -R, -1.f, -R};
  return t[k];
}

__global__ __launch_bounds__(256, 1) void pqn(const float* __restrict__ lr,
                                              float* __restrict__ out) {
  __shared__ alignas(16) float A[2 * AHI];     // 65536 B activations (fp32)
  __shared__ alignas(16) float WB[2][2048];    // 16384 B ring: 2 halves x 4 tiles

  const int tid = threadIdx.x;
  const int j   = tid & 3;
  const int pg  = (tid >> 2) & 7;      // pixel row (dy)
  const int cob = tid >> 5;            // 0..7

  // ---- swizzle: 4 siblings (same XCD) cover one 64B weight line
  const int n  = blockIdx.x;
  const int e2 = (n >> 3) & 3;
  const int P  = (n & 7) | ((n >> 5) << 3);   // 0..511
  const int jg = ((P & 3) << 2) | e2;         // 0..15
  const int i  = (P >> 2) & 63;
  const int b  = (P >> 8) & 1;

  const float* __restrict__ wb =
      lr + (size_t)b * NPAR * PLANE + (size_t)(i * 64 + jg * 4);
  const float* __restrict__ pt = wb + j;      // per-thread channel base

  float fyc, fys;
  sincosf(0.78539816339744830962f * pg, &fys, &fyc);

  const int abase = pg * 16 + j * 4;   // lane-contiguous A offset
  const int swz   = j * 4;             // weight-row XOR swizzle
  const int sq    = tid >> 7;          // staging: which tile-pair half
  const int sc    = tid & 127;         // staging channel within tile

  auto gaddr = [&](int g) -> size_t {  // first channel of group g's weights
    return 384 + (size_t)(g >> 3) * 4160 + (size_t)(g & 7) * 512;
  };

  float4 paA, paB;                     // single staging pair (1-group flight)
  {
    const size_t cb = gaddr(0);
    paA = *(const float4*)(wb + (cb + tid) * PLANE);
    paB = *(const float4*)(wb + (cb + 256 + tid) * PLANE);
  }
  float l0b[8], l0w[32], bb[8];
#pragma unroll
  for (int m = 0; m < 8; ++m) l0b[m] = pt[(size_t)(cob * 8 + m) * PLANE];
#pragma unroll
  for (int f = 0; f < 4; ++f)
#pragma unroll
    for (int m = 0; m < 8; ++m)
      l0w[f * 8 + m] = pt[(size_t)(64 + f * 64 + cob * 8 + m) * PLANE];
#pragma unroll
  for (int m = 0; m < 8; ++m) bb[m] = pt[(size_t)(320 + cob * 8 + m) * PLANE];

  // ---- L0 compute -> A
#pragma unroll
  for (int col = 0; col < 8; ++col) {
    float t[8];
#pragma unroll
    for (int k = 0; k < 8; ++k) {
      float v = l0b[col];
      v = fmaf(cx(k), l0w[col], v);
      v = fmaf(sx(k), l0w[8 + col], v);
      v = fmaf(fyc,  l0w[16 + col], v);
      v = fmaf(fys,  l0w[24 + col], v);
      t[k] = leaky(v);
    }
    float4 v0, v1;
    v0.x = t[0]; v0.y = t[1]; v0.z = t[2]; v0.w = t[3];
    v1.x = t[4]; v1.y = t[5]; v1.z = t[6]; v1.w = t[7];
    *(float4*)&A[(cob * 8 + col) * 128 + abase]       = v0;
    *(float4*)&A[(cob * 8 + col) * 128 + abase + AHI] = v1;
  }
  // publish group 0 -> half 0; refill Pa <- g1
#pragma unroll
  for (int jj = 0; jj < 4; ++jj) {
    WB[0][sq * 512       + jj * 128 + (sc ^ (jj * 4))] = ((const float*)&paA)[jj];
    WB[0][(2 + sq) * 512 + jj * 128 + (sc ^ (jj * 4))] = ((const float*)&paB)[jj];
  }
  {
    const size_t cb = gaddr(1);
    paA = *(const float4*)(wb + (cb + tid) * PLANE);
    paB = *(const float4*)(wb + (cb + 256 + tid) * PLANE);
  }
  asm volatile("s_waitcnt lgkmcnt(0)" ::: "memory");
  __builtin_amdgcn_s_barrier();
  __builtin_amdgcn_sched_barrier(0);

  float2 y2[32];                       // [col 0..7][k-pair 0..3]
#pragma unroll
  for (int m = 0; m < 32; ++m) y2[m] = make_float2(0.f, 0.f);

  // packed FMA block: y2[col][q] += aq[q] * w[col]  (w half via op_sel)
#define PKFM(A0, A1, W0, W1)                                                   \
  {                                                                            \
    const float2* a0p_ = (const float2*)&(A0);                                 \
    const float2* a1p_ = (const float2*)&(A1);                                 \
    const float2* w0p_ = (const float2*)&(W0);                                 \
    const float2* w1p_ = (const float2*)&(W1);                                 \
    const float2 aq_[4] = {a0p_[0], a0p_[1], a1p_[0], a1p_[1]};                \
    const float2 wp_[4] = {w0p_[0], w0p_[1], w1p_[0], w1p_[1]};                \
    _Pragma("unroll")                                                          \
    for (int col = 0; col < 8; ++col) {                                        \
      _Pragma("unroll")                                                        \
      for (int q = 0; q < 4; ++q) {                                            \
        if (col & 1)                                                           \
          asm("v_pk_fma_f32 %0, %1, %2, %0 op_sel:[0,1,0] op_sel_hi:[1,1,1]"   \
              : "+v"(y2[col * 4 + q]) : "v"(aq_[q]), "v"(wp_[col >> 1]));      \
        else                                                                   \
          asm("v_pk_fma_f32 %0, %1, %2, %0 op_sel:[0,0,0] op_sel_hi:[1,0,1]"   \
              : "+v"(y2[col * 4 + q]) : "v"(aq_[q]), "v"(wp_[col >> 1]));      \
      }                                                                        \
    }                                                                          \
  }

  // one full group: publish/refill, then depth-1 per-ci pipeline with pk-FMA
  auto group = [&](int g, int h) {     // h = g&1 (literal at call sites)
    const float* WH = WB[h];
    const int r0 = (g & 7) * 8;
    // prime ci-step 0
    float4 a0 = *(const float4*)&A[r0 * 128 + abase];
    float4 a1 = *(const float4*)&A[r0 * 128 + abase + AHI];
    float4 w0 = *(const float4*)&WH[j * 128 + ((cob * 8) ^ swz)];
    float4 w1 = *(const float4*)&WH[j * 128 + ((cob * 8 + 4) ^ swz)];
    if (g + 1 < 24) {                  // publish g+1 from Pa -> other half
      float* WD = WB[h ^ 1];
#pragma unroll
      for (int jj = 0; jj < 4; ++jj) {
        WD[sq * 512       + jj * 128 + (sc ^ (jj * 4))] = ((const float*)&paA)[jj];
        WD[(2 + sq) * 512 + jj * 128 + (sc ^ (jj * 4))] = ((const float*)&paB)[jj];
      }
    }
    if (g + 2 < 24) {                  // refill Pa <- g+2
      const size_t cb = gaddr(g + 2);
      paA = *(const float4*)(wb + (cb + tid) * PLANE);
      paB = *(const float4*)(wb + (cb + 256 + tid) * PLANE);
    }
#pragma unroll
    for (int t = 0; t < 8; ++t) {
      float4 na0, na1, nw0, nw1;
      if (t < 7) {                     // issue ci+1's reads BEFORE FMAs
        const int tn = t + 1;
        const int ci = r0 + tn;
        const int q = tn >> 1, cl = tn & 1;
        na0 = *(const float4*)&A[ci * 128 + abase];
        na1 = *(const float4*)&A[ci * 128 + abase + AHI];
        nw0 = *(const float4*)&WH[q * 512 + j * 128 + ((cl * 64 + cob * 8) ^ swz)];
        nw1 = *(const float4*)&WH[q * 512 + j * 128 + ((cl * 64 + cob * 8 + 4) ^ swz)];
      }
      PKFM(a0, a1, w0, w1)
      if (t < 7) { a0 = na0; a1 = na1; w0 = nw0; w1 = nw1; }
    }
    asm volatile("s_waitcnt lgkmcnt(0)" ::: "memory");
    __builtin_amdgcn_s_barrier();
    __builtin_amdgcn_sched_barrier(0);
  };
  auto flush = [&](int l) {            // layer end: bias + leaky -> A
#pragma unroll
    for (int col = 0; col < 8; ++col) {
      float4 v0, v1;
      v0.x = leaky(y2[col * 4 + 0].x + bb[col]);
      v0.y = leaky(y2[col * 4 + 0].y + bb[col]);
      v0.z = leaky(y2[col * 4 + 1].x + bb[col]);
      v0.w = leaky(y2[col * 4 + 1].y + bb[col]);
      v1.x = leaky(y2[col * 4 + 2].x + bb[col]);
      v1.y = leaky(y2[col * 4 + 2].y + bb[col]);
      v1.z = leaky(y2[col * 4 + 3].x + bb[col]);
      v1.w = leaky(y2[col * 4 + 3].y + bb[col]);
      *(float4*)&A[(cob * 8 + col) * 128 + abase]       = v0;
      *(float4*)&A[(cob * 8 + col) * 128 + abase + AHI] = v1;
    }
#pragma unroll
    for (int m = 0; m < 32; ++m) y2[m] = make_float2(0.f, 0.f);
    if (l < 2) {
#pragma unroll
      for (int m = 0; m < 8; ++m)
        bb[m] = pt[(size_t)(320 + (l + 1) * 4160 + cob * 8 + m) * PLANE];
    }
  };

  // ---- 12 super-iterations of 2 groups; ring half STATIC per position
#pragma unroll 1
  for (int u = 0; u < 12; ++u) {
    const int g0 = u * 2;
    group(g0, 0);
    const int g1 = g0 + 1;
    group(g1, 1);
    if ((g1 & 7) == 7) {               // layer end: flush + extra barrier
      flush(g1 >> 3);
      asm volatile("s_waitcnt lgkmcnt(0)" ::: "memory");
      __builtin_amdgcn_s_barrier();
      __builtin_amdgcn_sched_barrier(0);
    }
  }
#undef PKFM

  // ---- epilogue: L4 (64 -> 3) + tanh
  float po[24];
#pragma unroll
  for (int m = 0; m < 24; ++m) po[m] = 0.f;
#pragma unroll
  for (int cl = 0; cl < 8; ++cl) {
    const int ci = cob * 8 + cl;
    const float4 a0 = *(const float4*)&A[ci * 128 + abase];
    const float4 a1 = *(const float4*)&A[ci * 128 + abase + AHI];
#pragma unroll
    for (int o = 0; o < 3; ++o) {
      const float w = pt[(size_t)(12803 + ci * 3 + o) * PLANE];
      po[o * 8 + 0] = fmaf(a0.x, w, po[o * 8 + 0]);
      po[o * 8 + 1] = fmaf(a0.y, w, po[o * 8 + 1]);
      po[o * 8 + 2] = fmaf(a0.z, w, po[o * 8 + 2]);
      po[o * 8 + 3] = fmaf(a0.w, w, po[o * 8 + 3]);
      po[o * 8 + 4] = fmaf(a1.x, w, po[o * 8 + 4]);
      po[o * 8 + 5] = fmaf(a1.y, w, po[o * 8 + 5]);
      po[o * 8 + 6] = fmaf(a1.z, w, po[o * 8 + 6]);
      po[o * 8 + 7] = fmaf(a1.w, w, po[o * 8 + 7]);
    }
  }
  asm volatile("s_waitcnt lgkmcnt(0)" ::: "memory");
  __builtin_amdgcn_s_barrier();        // all A reads done -> reuse A
  float* R = A;
#pragma unroll
  for (int m = 0; m < 24; m += 4)
    *(float4*)&R[tid * 28 + m] = *(float4*)&po[m];
  asm volatile("s_waitcnt lgkmcnt(0)" ::: "memory");
  __builtin_amdgcn_s_barrier();
  __builtin_amdgcn_sched_barrier(0);

  if (cob == 0) {                      // tid < 32: one (j, pg) per thread
#pragma unroll
    for (int o = 0; o < 3; ++o) {
      const float bias = pt[(size_t)(12800 + o) * PLANE];
      float s[8];
#pragma unroll
      for (int k = 0; k < 8; ++k) s[k] = bias;
#pragma unroll
      for (int cb = 0; cb < 8; ++cb) {
#pragma unroll
        for (int k = 0; k < 8; ++k)
          s[k] += R[(cb * 32 + tid) * 28 + o * 8 + k];
      }
      float4 v0, v1;
      v0.x = tanhf(s[0]); v0.y = tanhf(s[1]); v0.z = tanhf(s[2]); v0.w = tanhf(s[3]);
      v1.x = tanhf(s[4]); v1.y = tanhf(s[5]); v1.z = tanhf(s[6]); v1.w = tanhf(s[7]);
      float* op = out + (size_t)b * 786432 + (size_t)o * 262144 +
                  (size_t)(i * 8 + pg) * 512 + (size_t)((jg * 4 + j) * 8);
      *(float4*)op = v0;
      *(float4*)(op + 4) = v1;
    }
  }
}

extern "C" void kernel_launch(void* const* d_in, const int* in_sizes, int n_in,
                              void* d_out, int out_size, void* d_ws, size_t ws_size,
                              hipStream_t stream) {
  (void)in_sizes; (void)n_in; (void)d_ws; (void)ws_size; (void)out_size;
  const float* lr = (const float*)d_in[1];  // d_in[0] = highres (unused by the math)
  float* out = (float*)d_out;
  hipLaunchKernelGGL(pqn, dim3(2048), dim3(256), 0, stream, lr, out);
}